// Round 14
// baseline (390.095 us; speedup 1.0000x reference)
//
#include <hip/hip_runtime.h>
#include <hip/hip_bf16.h>

#define DIM 256
#define NH 8

typedef __attribute__((ext_vector_type(4))) float f32x4;
typedef __attribute__((ext_vector_type(8))) short bf16x8;
typedef __attribute__((ext_vector_type(8))) unsigned short u16x8;

__device__ __forceinline__ float bf2f(unsigned short u) {
    union { unsigned int i; float f; } x; x.i = ((unsigned int)u) << 16; return x.f;
}
__device__ __forceinline__ unsigned short f2bf(float f) {
    union { float f; unsigned int i; } x; x.f = f;
    unsigned int r = x.i + 0x7fffu + ((x.i >> 16) & 1u);
    return (unsigned short)(r >> 16);
}

// ---------------------------------------------------------------------------
// Layouts + col-banded CSR (round-13) + 2-phase pipelined GEMM:
// QKV record per node (768 bf16): [0..255]=Q head-contig, [256..767]=KV
// lane-interleaved (lane l owns {k[4l..4l+3], v[4l..4l+3]} = 16B).
// Tiled GEMM operand layout: off(R,ks,kb,row,j)=R*32768+ks*8192+kb*1024+row*8+j
// Edge sort: coarse buckets of 512 rows; fine key = (row, col-band), FB=28
// bands (~2.7MB KV per band < 4MB per-XCD L2) -> resident attn waves sweep a
// shared L2-sized col window.
// GEMM: double-buffered LDS (2x32KB); per K-step: STAGE(next) -> MFMA(cur) ->
// one __syncthreads (vmcnt0+barrier). Prefetch flies under MFMA.
// GEMM epilogue: LDS round-trip (XOR-16B swizzle) -> dwordx4 global stores.
// ---------------------------------------------------------------------------
__device__ __forceinline__ void map_col(int o, int& which, int& c) {
    int cp;
    if (o < 256) { which = 0; cp = o; }
    else {
        int u = o - 256;
        int lane = u >> 3, slot = u & 7;
        which = (slot < 4) ? 1 : 2;
        cp = lane * 4 + (slot & 3);
    }
    c = (cp & 31) * 8 + (cp >> 5);   // reference reshape: c = d*NH + h
}

// Fused prep: WqkvT (tiled), WoT (tiled), bqkv, and x -> tiled bf16.
#define PREP_W0 262912
__global__ void prep_fused(const float* __restrict__ Wq, const float* __restrict__ Wk,
                           const float* __restrict__ Wv, const float* __restrict__ Wo,
                           const float* __restrict__ bq, const float* __restrict__ bk,
                           const float* __restrict__ bv, const float* __restrict__ x,
                           unsigned short* __restrict__ WqkvT,
                           unsigned short* __restrict__ WoT,
                           float* __restrict__ bqkv,
                           unsigned short* __restrict__ xt, int M) {
    int idx = blockIdx.x * 256 + threadIdx.x;
    if (idx < 768 * 256) {
        int CB = idx >> 15;
        int rem = idx & 32767;
        int ks = rem >> 13, kb = (rem >> 10) & 7, ci = (rem >> 3) & 127, jj = rem & 7;
        int o = CB * 128 + ci;
        int k = ks * 64 + kb * 8 + jj;
        int which, c; map_col(o, which, c);
        const float* W = (which == 0) ? Wq : (which == 1 ? Wk : Wv);
        float scale = (which == 0) ? 0.17677669529663687f : 1.0f;
        WqkvT[idx] = f2bf(W[k * DIM + c] * scale);
    } else if (idx < 768 * 256 + 256 * 256) {
        int id2 = idx - 768 * 256;
        int CB = id2 >> 15;
        int rem = id2 & 32767;
        int ks = rem >> 13, kb = (rem >> 10) & 7, ci = (rem >> 3) & 127, jj = rem & 7;
        int o = CB * 128 + ci;
        int cp = ks * 64 + kb * 8 + jj;
        WoT[id2] = f2bf(Wo[((cp & 31) * 8 + (cp >> 5)) * DIM + o]);
    } else if (idx < PREP_W0) {
        int o = idx - (768 * 256 + 256 * 256);
        if (o < 768) {
            int which, c; map_col(o, which, c);
            const float* b = (which == 0) ? bq : (which == 1 ? bk : bv);
            float scale = (which == 0) ? 0.17677669529663687f : 1.0f;
            bqkv[o] = b[c] * scale;
        }
    } else {
        int t = idx - PREP_W0;
        int r = t >> 5;
        if (r >= M) return;
        int kc = (t & 31) * 8;
        float4 v0 = *reinterpret_cast<const float4*>(x + (size_t)r * DIM + kc);
        float4 v1 = *reinterpret_cast<const float4*>(x + (size_t)r * DIM + kc + 4);
        u16x8 o;
        o[0] = f2bf(v0.x); o[1] = f2bf(v0.y); o[2] = f2bf(v0.z); o[3] = f2bf(v0.w);
        o[4] = f2bf(v1.x); o[5] = f2bf(v1.y); o[6] = f2bf(v1.z); o[7] = f2bf(v1.w);
        int R = r >> 7, row = r & 127, ks = kc >> 6, kb = (kc & 63) >> 3;
        *reinterpret_cast<u16x8*>(xt + (size_t)R * 32768 + ks * 8192 + kb * 1024 + row * 8) = o;
    }
}

// ---------------------------------------------------------------------------
// LDS-staged MFMA GEMM. 128x128 tile, 4 waves, BK=64, 64KB LDS double-buffer.
// Per K-step: STAGE(next buf) -> ds_read+MFMA(cur) -> __syncthreads().
// (The barrier's implicit vmcnt(0) drains the prefetch, which flew under the
// MFMAs; the previous barrier guarantees the overwritten buffer's ds_reads
// are complete -> single barrier per step.)
// Bijective XCD swizzle; LDS-round-trip vectorized epilogue.
// ---------------------------------------------------------------------------
#define GLOAD_LDS16(gp, lp) \
    __builtin_amdgcn_global_load_lds( \
        (const __attribute__((address_space(1))) unsigned int*)(gp), \
        (__attribute__((address_space(3))) unsigned int*)(lp), 16, 0, 0)

template<int OUT_BF16, int CT>
__global__ __launch_bounds__(256) void gemm_tiled(
    const unsigned short* __restrict__ At, const unsigned short* __restrict__ Bt,
    const float* __restrict__ bias, void* __restrict__ Cout, int M, int ldc) {
    __shared__ unsigned short lds[32768];          // 64KB: buf0 @0, buf1 @16384
    int tid = threadIdx.x;
    int l = tid & 63, w = tid >> 6;

    // bijective XCD swizzle: orig%8 = physical XCD (round-robin dispatch)
    int nwg = gridDim.x;
    int q = nwg >> 3, r8 = nwg & 7;
    int xcd = blockIdx.x & 7, pos = blockIdx.x >> 3;
    int wg = (xcd < r8 ? xcd * (q + 1) : r8 * (q + 1) + (xcd - r8) * q) + pos;
    int xtile = wg / CT, ctile = wg % CT;

    const unsigned short* Abase = At + (size_t)xtile * 32768;
    const unsigned short* Bbase = Bt + (size_t)ctile * 32768;

    int rbase = (w >> 1) * 64 + (l & 15);
    int cbase = (w & 1) * 64 + (l & 15);
    int kq = l >> 4;

    auto stage = [&](int ks, int buf) {
        unsigned short* lb = &lds[buf * 16384];
#pragma unroll
        for (int i = 0; i < 4; ++i) {
            GLOAD_LDS16(Abase + (size_t)ks * 8192 + i * 2048 + tid * 8, &lb[i * 2048 + tid * 8]);
            GLOAD_LDS16(Bbase + (size_t)ks * 8192 + i * 2048 + tid * 8, &lb[8192 + i * 2048 + tid * 8]);
        }
    };

    f32x4 acc[4][4] = {};
    stage(0, 0);
    __syncthreads();                               // buf0 ready
#pragma unroll
    for (int ks = 0; ks < 4; ++ks) {
        if (ks < 3) stage(ks + 1, (ks + 1) & 1);   // prefetch next (flies under MFMA)
        const unsigned short* lb = &lds[(ks & 1) * 16384];
#pragma unroll
        for (int kk = 0; kk < 2; ++kk) {
            int kb = kk * 4 + kq;
            bf16x8 a[4], b[4];
#pragma unroll
            for (int m = 0; m < 4; ++m)
                a[m] = *reinterpret_cast<const bf16x8*>(&lb[kb * 1024 + (rbase + m * 16) * 8]);
#pragma unroll
            for (int n = 0; n < 4; ++n)
                b[n] = *reinterpret_cast<const bf16x8*>(&lb[8192 + kb * 1024 + (cbase + n * 16) * 8]);
#pragma unroll
            for (int m = 0; m < 4; ++m)
#pragma unroll
                for (int n = 0; n < 4; ++n)
                    acc[m][n] = __builtin_amdgcn_mfma_f32_16x16x32_bf16(a[m], b[n], acc[m][n], 0, 0, 0);
        }
        __syncthreads();                           // drain prefetch + close WAR
    }

    // ---- epilogue: LDS round-trip -> vectorized stores ----
    int rb = (l >> 4) * 4, cc = l & 15;
    char* lc = (char*)lds;

    if (OUT_BF16) {
        // 128x128 bf16 tile = 32KB (buffer 0), one pass. XOR-16B swizzle.
#pragma unroll
        for (int n = 0; n < 4; ++n) {
            int c_blk = (w & 1) * 64 + n * 16 + cc;
            float bv = bias[ctile * 128 + c_blk];
#pragma unroll
            for (int m = 0; m < 4; ++m) {
#pragma unroll
                for (int j = 0; j < 4; ++j) {
                    int r_blk = (w >> 1) * 64 + m * 16 + rb + j;
                    int byte = r_blk * 256 + ((((c_blk * 2) >> 4) ^ (r_blk & 7)) << 4) + ((c_blk * 2) & 15);
                    *reinterpret_cast<unsigned short*>(lc + byte) = f2bf(acc[m][n][j] + bv);
                }
            }
        }
        __syncthreads();
        int r2 = tid >> 1;
        int gr = xtile * 128 + r2;
#pragma unroll
        for (int i = 0; i < 8; ++i) {
            int ch = (tid & 1) * 8 + i;
            uint4 v = *reinterpret_cast<uint4*>(lc + r2 * 256 + ((ch ^ (r2 & 7)) << 4));
            if (gr < M)
                *reinterpret_cast<uint4*>((unsigned short*)Cout + (size_t)gr * ldc + ctile * 128 + ch * 8) = v;
        }
    } else {
        // f32: two 32KB passes (rows 0-63 by waves 0,1; rows 64-127 by 2,3).
#pragma unroll
        for (int p = 0; p < 2; ++p) {
            __syncthreads();
            if ((w >> 1) == p) {
#pragma unroll
                for (int n = 0; n < 4; ++n) {
                    int c_blk = (w & 1) * 64 + n * 16 + cc;
                    float bv = bias[ctile * 128 + c_blk];
#pragma unroll
                    for (int m = 0; m < 4; ++m) {
#pragma unroll
                        for (int j = 0; j < 4; ++j) {
                            int rl = m * 16 + rb + j;           // 0..63
                            int byte = rl * 512 + ((((c_blk * 4) >> 4) ^ (rl & 7)) << 4) + ((c_blk * 4) & 15);
                            *reinterpret_cast<float*>(lc + byte) = acc[m][n][j] + bv;
                        }
                    }
                }
            }
            __syncthreads();
            int rl = tid >> 2;
            int gr = xtile * 128 + p * 64 + rl;
#pragma unroll
            for (int i = 0; i < 8; ++i) {
                int ch = (tid & 3) * 8 + i;
                uint4 v = *reinterpret_cast<uint4*>(lc + rl * 512 + ((ch ^ (rl & 7)) << 4));
                if (gr < M)
                    *reinterpret_cast<uint4*>((float*)Cout + (size_t)gr * ldc + ctile * 128 + ch * 4) = v;
            }
        }
    }
}

// ---------------------------------------------------------------------------
// Edge multisplit + CSR, all derived from per-block coarse histograms.
// ---------------------------------------------------------------------------
#define EPB 4096
#define NBMAX 128
#define FB 28            // fine col bands (~2.7MB KV per band < 4MB L2)

__global__ __launch_bounds__(256) void hist_coarse(const int* __restrict__ row,
                                                   int* __restrict__ H, int E, int nblk, int NB) {
    __shared__ int h[NBMAX];
    int tid = threadIdx.x, blk = blockIdx.x;
    for (int b = tid; b < NB; b += 256) h[b] = 0;
    __syncthreads();
    int base = blk * EPB;
    int nloc = min(EPB, E - base);
    for (int k = tid; k < nloc; k += 256) atomicAdd(&h[row[base + k] >> 9], 1);
    __syncthreads();
    for (int b = tid; b < NB; b += 256) H[b * nblk + blk] = h[b];
}

__global__ __launch_bounds__(256) void bucket_totals(const int* __restrict__ H,
                                                     int* __restrict__ Tb, int nblk) {
    __shared__ int ws[4];
    int b = blockIdx.x, tid = threadIdx.x;
    int s = 0;
    for (int k = tid; k < nblk; k += 256) s += H[b * nblk + k];
#pragma unroll
    for (int off = 1; off < 64; off <<= 1) s += __shfl_xor(s, off, 64);
    if ((tid & 63) == 0) ws[tid >> 6] = s;
    __syncthreads();
    if (tid == 0) Tb[b] = ws[0] + ws[1] + ws[2] + ws[3];
}

__global__ void scan_buckets(const int* __restrict__ Tb, int* __restrict__ Cbase,
                             int NB, int* __restrict__ rowptr, int N) {
    int l = threadIdx.x;
    int carry = 0;
    for (int base = 0; base < NB; base += 64) {
        int idx = base + l;
        int v = (idx < NB) ? Tb[idx] : 0;
        int s = v;
#pragma unroll
        for (int off = 1; off < 64; off <<= 1) {
            int u = __shfl_up(s, off, 64);
            if (l >= off) s += u;
        }
        if (idx < NB) Cbase[idx] = s - v + carry;
        carry += __shfl(s, 63, 64);
    }
    if (l == 0) { Cbase[NB] = carry; rowptr[N] = carry; }
}

__global__ void scan_coarse(int* __restrict__ H, const int* __restrict__ Cbase, int nblk) {
    int b = blockIdx.x, l = threadIdx.x;
    int carry = Cbase[b];
    for (int s0 = 0; s0 < nblk; s0 += 64) {
        int idx = s0 + l;
        int v = (idx < nblk) ? H[b * nblk + idx] : 0;
        int s = v;
#pragma unroll
        for (int off = 1; off < 64; off <<= 1) {
            int u = __shfl_up(s, off, 64);
            if (l >= off) s += u;
        }
        if (idx < nblk) H[b * nblk + idx] = s - v + carry;
        carry += __shfl(s, 63, 64);
    }
}

__global__ __launch_bounds__(256) void scatter_coarse(const int* __restrict__ row,
                                                      const int* __restrict__ col,
                                                      const int* __restrict__ H,
                                                      unsigned* __restrict__ ebuf,
                                                      int E, int nblk, int NB) {
    __shared__ int h[NBMAX];
    __shared__ int lofs[NBMAX + 1];
    __shared__ int dstv[NBMAX];
    __shared__ unsigned rin[EPB];
    __shared__ unsigned rsort[EPB];
    int tid = threadIdx.x, blk = blockIdx.x;
    int base = blk * EPB;
    int nloc = min(EPB, E - base);

    for (int b = tid; b < NB; b += 256) h[b] = 0;
    __syncthreads();
    for (int k = tid; k < nloc; k += 256) {
        int r = row[base + k], c = col[base + k];
        rin[k] = ((unsigned)r << 16) | (unsigned)c;
        atomicAdd(&h[r >> 9], 1);
    }
    __syncthreads();
    if (tid == 0) {
        int run = 0;
        for (int b = 0; b < NB; ++b) { lofs[b] = run; run += h[b]; }
        lofs[NB] = run;
    }
    __syncthreads();
    for (int b = tid; b < NB; b += 256) { h[b] = lofs[b]; dstv[b] = H[b * nblk + blk]; }
    __syncthreads();
    for (int k = tid; k < nloc; k += 256) {
        unsigned rec = rin[k];
        int pos = atomicAdd(&h[rec >> 25], 1);
        rsort[pos] = rec;
    }
    __syncthreads();
    // parallel copy-out: thread k finds its bucket by binary search in lofs
    for (int k = tid; k < nloc; k += 256) {
        int lo = 0, hi = NB;
        while (hi - lo > 1) {
            int mid = (lo + hi) >> 1;
            if (lofs[mid] <= k) lo = mid; else hi = mid;
        }
        ebuf[dstv[lo] + (k - lofs[lo])] = rsort[k];
    }
}

// Fine pass per coarse bucket, keyed by (row, col-band): LDS segment
// histogram (512*FB) -> block exclusive scan -> rowptr -> banded scatter.
__global__ __launch_bounds__(256) void fine_fused(const unsigned* __restrict__ ebuf,
                                                  const int* __restrict__ Cbase,
                                                  int* __restrict__ rowptr,
                                                  int* __restrict__ ecol, int N) {
    __shared__ int lseg[512 * FB];                 // 56 KB: counts -> cursors
    __shared__ int ws[4];
    int b = blockIdx.x, tid = threadIdx.x, l = tid & 63, w = tid >> 6;
    int row0 = b << 9;
    int nr = min(512, N - row0);
    int base = Cbase[b], endp = Cbase[b + 1];

    for (int s = tid; s < 512 * FB; s += 256) lseg[s] = 0;
    __syncthreads();
    for (int k = base + tid; k < endp; k += 256) {
        unsigned rec = ebuf[k];
        int r = (rec >> 16) - row0;
        int band = ((rec & 0xFFFFu) * FB) >> 16;
        atomicAdd(&lseg[r * FB + band], 1);
    }
    __syncthreads();

    // block exclusive scan over 512*FB elements; thread owns contiguous chunk
    const int CH = 512 * FB / 256;                 // 56 per thread
    int base_t = tid * CH;
    int sum = 0;
#pragma unroll
    for (int u = 0; u < CH; ++u) sum += lseg[base_t + u];
    int s = sum;
#pragma unroll
    for (int off = 1; off < 64; off <<= 1) {
        int u = __shfl_up(s, off, 64);
        if (l >= off) s += u;
    }
    if (l == 63) ws[w] = s;
    __syncthreads();
    int woff = 0;
    for (int k = 0; k < w; ++k) woff += ws[k];
    int run = woff + s - sum;                      // exclusive prefix of chunk
#pragma unroll
    for (int u = 0; u < CH; ++u) {
        int c = lseg[base_t + u];
        lseg[base_t + u] = run;
        run += c;
    }
    __syncthreads();

    // rowptr: row r starts at its band-0 segment
    for (int r = tid; r < nr; r += 256) rowptr[row0 + r] = base + lseg[r * FB];
    __syncthreads();

    // banded scatter
    for (int k = base + tid; k < endp; k += 256) {
        unsigned rec = ebuf[k];
        int r = (rec >> 16) - row0;
        unsigned c = rec & 0xFFFFu;
        int band = (c * FB) >> 16;
        int rel = atomicAdd(&lseg[r * FB + band], 1);
        ecol[base + rel] = (int)c;
    }
}

// ---------------------------------------------------------------------------
// Fused sparse attention, one wave per node, depth-4 KV pipeline with a
// clamped column ring. Single launch (round-10 known-good).
// ---------------------------------------------------------------------------
__global__ __launch_bounds__(256) void attn_fused(
    const unsigned short* __restrict__ QKV,
    const int* __restrict__ rowptr, const int* __restrict__ ecol,
    unsigned short* __restrict__ attn_t, int N) {
    int i = blockIdx.x * 4 + (threadIdx.x >> 6);
    if (i >= N) return;
    int l = threadIdx.x & 63;

    ushort4 q4 = *reinterpret_cast<const ushort4*>(QKV + (size_t)i * 768 + l * 4);
    float q0 = bf2f(q4.x), q1 = bf2f(q4.y), q2 = bf2f(q4.z), q3 = bf2f(q4.w);

    int j = rowptr[i], end = rowptr[i + 1];
    float z = 0.f, a0 = 0.f, a1 = 0.f, a2 = 0.f, a3 = 0.f;

    if (j < end) {
        int last = end - 1;
#define CL(jj) ecol[(jj) < last ? (jj) : last]
#define KVL(c) (*reinterpret_cast<const u16x8*>(QKV + (size_t)(c) * 768 + 256 + l * 8))
        int cA = CL(j), cB = CL(j + 1), cC = CL(j + 2), cD = CL(j + 3);
        u16x8 kvA = KVL(cA), kvB = KVL(cB), kvC = KVL(cC), kvD = KVL(cD);
        int r0 = CL(j + 4), r1 = CL(j + 5), r2 = CL(j + 6), r3 = CL(j + 7);

#define STEP(KV) { \
        float s = q0 * bf2f(KV[0]) + q1 * bf2f(KV[1]) + q2 * bf2f(KV[2]) + q3 * bf2f(KV[3]); \
        s += __shfl_xor(s, 1, 64); \
        s += __shfl_xor(s, 2, 64); \
        s += __shfl_xor(s, 4, 64); \
        float wgt = __expf(s); \
        z += wgt; \
        a0 += wgt * bf2f(KV[4]); a1 += wgt * bf2f(KV[5]); \
        a2 += wgt * bf2f(KV[6]); a3 += wgt * bf2f(KV[7]); \
        KV = KVL(r0); r0 = r1; r1 = r2; r2 = r3; r3 = CL(j + 8); \
        ++j; }

        while (j < end) {
            STEP(kvA);
            if (j < end) STEP(kvB);
            if (j < end) STEP(kvC);
            if (j < end) STEP(kvD);
        }
#undef STEP
#undef KVL
#undef CL
    }

    float inv = (z > 0.f) ? 1.0f / z : 0.f;
    ushort4 o;
    o.x = f2bf(a0 * inv); o.y = f2bf(a1 * inv);
    o.z = f2bf(a2 * inv); o.w = f2bf(a3 * inv);
    int R = i >> 7, row = i & 127;
    int ks = l >> 4, kb = (l & 15) >> 1, j4 = (l & 1) * 4;
    *reinterpret_cast<ushort4*>(attn_t + (size_t)R * 32768 + ks * 8192 + kb * 1024 + row * 8 + j4) = o;
}

// ---------------------------------------------------------------------------
// Launch
// ---------------------------------------------------------------------------
extern "C" void kernel_launch(void* const* d_in, const int* in_sizes, int n_in,
                              void* d_out, int out_size, void* d_ws, size_t ws_size,
                              hipStream_t stream) {
    const float* x  = (const float*)d_in[0];
    const int*   row = (const int*)d_in[1];
    const int*   col = (const int*)d_in[2];
    const float* Wq = (const float*)d_in[3];
    const float* bq = (const float*)d_in[4];
    const float* Wk = (const float*)d_in[5];
    const float* bk = (const float*)d_in[6];
    const float* Wv = (const float*)d_in[7];
    const float* bv = (const float*)d_in[8];
    const float* Wo = (const float*)d_in[9];
    const float* bo = (const float*)d_in[10];
    int N = in_sizes[0] / DIM;
    int E = in_sizes[1];
    float* out = (float*)d_out;

    int Rtiles = (N + 127) / 128;
    int NB = (N + 511) >> 9;                       // coarse buckets (98)
    int nblk = (E + EPB - 1) / EPB;                // multisplit blocks (391)

    char* p = (char*)d_ws;
    auto alloc = [&](size_t bytes) {
        char* r = p;
        p += (bytes + 255) & ~(size_t)255;
        return r;
    };
    unsigned short* xt     = (unsigned short*)alloc((size_t)Rtiles * 32768 * 2);
    unsigned short* QKV    = (unsigned short*)alloc((size_t)N * 768 * 2);
    unsigned short* attn_t = (unsigned short*)alloc((size_t)Rtiles * 32768 * 2);
    unsigned short* WqkvT  = (unsigned short*)alloc((size_t)768 * DIM * 2);
    unsigned short* WoT    = (unsigned short*)alloc((size_t)DIM * DIM * 2);
    float* bqkv = (float*)alloc(768 * sizeof(float));
    int* rowptr = (int*)alloc((size_t)(N + 1) * sizeof(int));
    int* H      = (int*)alloc((size_t)NB * nblk * sizeof(int));
    int* Tb     = (int*)alloc((size_t)NB * sizeof(int));
    int* Cbase  = (int*)alloc((size_t)(NB + 1) * sizeof(int));
    unsigned* ebuf = (unsigned*)alloc((size_t)E * sizeof(unsigned));
    int* ecol   = (int*)alloc((size_t)E * sizeof(int));

    // fused prep: weights + biases + x conversion
    int prep_items = PREP_W0 + N * 32;
    prep_fused<<<(prep_items + 255) / 256, 256, 0, stream>>>(
        Wq, Wk, Wv, Wo, bq, bk, bv, x, WqkvT, WoT, bqkv, xt, N);

    // multisplit-derived CSR (col-banded fine order)
    hist_coarse<<<nblk, 256, 0, stream>>>(row, H, E, nblk, NB);
    bucket_totals<<<NB, 256, 0, stream>>>(H, Tb, nblk);
    scan_buckets<<<1, 64, 0, stream>>>(Tb, Cbase, NB, rowptr, N);
    scan_coarse<<<NB, 64, 0, stream>>>(H, Cbase, nblk);
    scatter_coarse<<<nblk, 256, 0, stream>>>(row, col, H, ebuf, E, nblk, NB);
    fine_fused<<<NB, 256, 0, stream>>>(ebuf, Cbase, rowptr, ecol, N);

    // fused QKV projection -> bf16 records [N][768]  (XCD-swizzled)
    gemm_tiled<1, 6><<<Rtiles * 6, 256, 0, stream>>>(xt, WqkvT, bqkv, QKV, N, 768);

    // fused sparse attention (single launch)
    attn_fused<<<(N + 3) / 4, 256, 0, stream>>>(QKV, rowptr, ecol, attn_t, N);

    // output projection -> f32 out  (XCD-swizzled)
    gemm_tiled<0, 2><<<Rtiles * 2, 256, 0, stream>>>(attn_t, WoT, bo, out, N, DIM);
}

// Round 15
// 381.583 us; speedup vs baseline: 1.0223x; 1.0223x over previous
//
#include <hip/hip_runtime.h>
#include <hip/hip_bf16.h>

#define DIM 256
#define NH 8

typedef __attribute__((ext_vector_type(4))) float f32x4;
typedef __attribute__((ext_vector_type(8))) short bf16x8;
typedef __attribute__((ext_vector_type(8))) unsigned short u16x8;

__device__ __forceinline__ float bf2f(unsigned short u) {
    union { unsigned int i; float f; } x; x.i = ((unsigned int)u) << 16; return x.f;
}
__device__ __forceinline__ unsigned short f2bf(float f) {
    union { float f; unsigned int i; } x; x.f = f;
    unsigned int r = x.i + 0x7fffu + ((x.i >> 16) & 1u);
    return (unsigned short)(r >> 16);
}

// ---------------------------------------------------------------------------
// Round-13 configuration (session best: 385 µs).
// QKV record per node (768 bf16): [0..255]=Q head-contig, [256..767]=KV
// lane-interleaved (lane l owns {k[4l..4l+3], v[4l..4l+3]} = 16B).
// Tiled GEMM operand layout: off(R,ks,kb,row,j)=R*32768+ks*8192+kb*1024+row*8+j
// Edge sort: coarse buckets of 512 rows; fine key = (row, col-band), FB=16.
// GEMM: single-buffered 32KB LDS (4-5 blocks/CU inter-block overlap beats
// explicit pipelining -- verified rounds 4/11/14); XCD swizzle; LDS round-trip
// epilogue (XOR-16B swizzle) -> dwordx4 stores.
// ---------------------------------------------------------------------------
__device__ __forceinline__ void map_col(int o, int& which, int& c) {
    int cp;
    if (o < 256) { which = 0; cp = o; }
    else {
        int u = o - 256;
        int lane = u >> 3, slot = u & 7;
        which = (slot < 4) ? 1 : 2;
        cp = lane * 4 + (slot & 3);
    }
    c = (cp & 31) * 8 + (cp >> 5);   // reference reshape: c = d*NH + h
}

// Fused prep: WqkvT (tiled), WoT (tiled), bqkv, and x -> tiled bf16.
#define PREP_W0 262912
__global__ void prep_fused(const float* __restrict__ Wq, const float* __restrict__ Wk,
                           const float* __restrict__ Wv, const float* __restrict__ Wo,
                           const float* __restrict__ bq, const float* __restrict__ bk,
                           const float* __restrict__ bv, const float* __restrict__ x,
                           unsigned short* __restrict__ WqkvT,
                           unsigned short* __restrict__ WoT,
                           float* __restrict__ bqkv,
                           unsigned short* __restrict__ xt, int M) {
    int idx = blockIdx.x * 256 + threadIdx.x;
    if (idx < 768 * 256) {
        int CB = idx >> 15;
        int rem = idx & 32767;
        int ks = rem >> 13, kb = (rem >> 10) & 7, ci = (rem >> 3) & 127, jj = rem & 7;
        int o = CB * 128 + ci;
        int k = ks * 64 + kb * 8 + jj;
        int which, c; map_col(o, which, c);
        const float* W = (which == 0) ? Wq : (which == 1 ? Wk : Wv);
        float scale = (which == 0) ? 0.17677669529663687f : 1.0f;
        WqkvT[idx] = f2bf(W[k * DIM + c] * scale);
    } else if (idx < 768 * 256 + 256 * 256) {
        int id2 = idx - 768 * 256;
        int CB = id2 >> 15;
        int rem = id2 & 32767;
        int ks = rem >> 13, kb = (rem >> 10) & 7, ci = (rem >> 3) & 127, jj = rem & 7;
        int o = CB * 128 + ci;
        int cp = ks * 64 + kb * 8 + jj;
        WoT[id2] = f2bf(Wo[((cp & 31) * 8 + (cp >> 5)) * DIM + o]);
    } else if (idx < PREP_W0) {
        int o = idx - (768 * 256 + 256 * 256);
        if (o < 768) {
            int which, c; map_col(o, which, c);
            const float* b = (which == 0) ? bq : (which == 1 ? bk : bv);
            float scale = (which == 0) ? 0.17677669529663687f : 1.0f;
            bqkv[o] = b[c] * scale;
        }
    } else {
        int t = idx - PREP_W0;
        int r = t >> 5;
        if (r >= M) return;
        int kc = (t & 31) * 8;
        float4 v0 = *reinterpret_cast<const float4*>(x + (size_t)r * DIM + kc);
        float4 v1 = *reinterpret_cast<const float4*>(x + (size_t)r * DIM + kc + 4);
        u16x8 o;
        o[0] = f2bf(v0.x); o[1] = f2bf(v0.y); o[2] = f2bf(v0.z); o[3] = f2bf(v0.w);
        o[4] = f2bf(v1.x); o[5] = f2bf(v1.y); o[6] = f2bf(v1.z); o[7] = f2bf(v1.w);
        int R = r >> 7, row = r & 127, ks = kc >> 6, kb = (kc & 63) >> 3;
        *reinterpret_cast<u16x8*>(xt + (size_t)R * 32768 + ks * 8192 + kb * 1024 + row * 8) = o;
    }
}

// ---------------------------------------------------------------------------
// LDS-staged MFMA GEMM. 128x128 tile, 4 waves, BK=64, 32KB LDS.
// Bijective XCD swizzle; LDS-round-trip vectorized epilogue.
// ---------------------------------------------------------------------------
#define GLOAD_LDS16(gp, lp) \
    __builtin_amdgcn_global_load_lds( \
        (const __attribute__((address_space(1))) unsigned int*)(gp), \
        (__attribute__((address_space(3))) unsigned int*)(lp), 16, 0, 0)

template<int OUT_BF16, int CT>
__global__ __launch_bounds__(256) void gemm_tiled(
    const unsigned short* __restrict__ At, const unsigned short* __restrict__ Bt,
    const float* __restrict__ bias, void* __restrict__ Cout, int M, int ldc) {
    __shared__ unsigned short lds[16384];          // 32KB: A 16KB @0, B 16KB @8192
    int tid = threadIdx.x;
    int l = tid & 63, w = tid >> 6;

    // bijective XCD swizzle: orig%8 = physical XCD (round-robin dispatch)
    int nwg = gridDim.x;
    int q = nwg >> 3, r8 = nwg & 7;
    int xcd = blockIdx.x & 7, pos = blockIdx.x >> 3;
    int wg = (xcd < r8 ? xcd * (q + 1) : r8 * (q + 1) + (xcd - r8) * q) + pos;
    int xtile = wg / CT, ctile = wg % CT;

    const unsigned short* Abase = At + (size_t)xtile * 32768;
    const unsigned short* Bbase = Bt + (size_t)ctile * 32768;

    int rbase = (w >> 1) * 64 + (l & 15);
    int cbase = (w & 1) * 64 + (l & 15);
    int kq = l >> 4;

    f32x4 acc[4][4] = {};
#pragma unroll
    for (int ks = 0; ks < 4; ++ks) {
        if (ks) __syncthreads();
#pragma unroll
        for (int i = 0; i < 4; ++i) {
            GLOAD_LDS16(Abase + (size_t)ks * 8192 + i * 2048 + tid * 8, &lds[i * 2048 + tid * 8]);
            GLOAD_LDS16(Bbase + (size_t)ks * 8192 + i * 2048 + tid * 8, &lds[8192 + i * 2048 + tid * 8]);
        }
        __syncthreads();
#pragma unroll
        for (int kk = 0; kk < 2; ++kk) {
            int kb = kk * 4 + kq;
            bf16x8 a[4], b[4];
#pragma unroll
            for (int m = 0; m < 4; ++m)
                a[m] = *reinterpret_cast<const bf16x8*>(&lds[kb * 1024 + (rbase + m * 16) * 8]);
#pragma unroll
            for (int n = 0; n < 4; ++n)
                b[n] = *reinterpret_cast<const bf16x8*>(&lds[8192 + kb * 1024 + (cbase + n * 16) * 8]);
#pragma unroll
            for (int m = 0; m < 4; ++m)
#pragma unroll
                for (int n = 0; n < 4; ++n)
                    acc[m][n] = __builtin_amdgcn_mfma_f32_16x16x32_bf16(a[m], b[n], acc[m][n], 0, 0, 0);
        }
    }

    // ---- epilogue: LDS round-trip -> vectorized stores ----
    int rb = (l >> 4) * 4, cc = l & 15;
    char* lc = (char*)lds;

    if (OUT_BF16) {
        __syncthreads();                           // all K-loop LDS reads done
#pragma unroll
        for (int n = 0; n < 4; ++n) {
            int c_blk = (w & 1) * 64 + n * 16 + cc;
            float bv = bias[ctile * 128 + c_blk];
#pragma unroll
            for (int m = 0; m < 4; ++m) {
#pragma unroll
                for (int j = 0; j < 4; ++j) {
                    int r_blk = (w >> 1) * 64 + m * 16 + rb + j;
                    int byte = r_blk * 256 + ((((c_blk * 2) >> 4) ^ (r_blk & 7)) << 4) + ((c_blk * 2) & 15);
                    *reinterpret_cast<unsigned short*>(lc + byte) = f2bf(acc[m][n][j] + bv);
                }
            }
        }
        __syncthreads();
        int r2 = tid >> 1;
        int gr = xtile * 128 + r2;
#pragma unroll
        for (int i = 0; i < 8; ++i) {
            int ch = (tid & 1) * 8 + i;
            uint4 v = *reinterpret_cast<uint4*>(lc + r2 * 256 + ((ch ^ (r2 & 7)) << 4));
            if (gr < M)
                *reinterpret_cast<uint4*>((unsigned short*)Cout + (size_t)gr * ldc + ctile * 128 + ch * 8) = v;
        }
    } else {
        // f32: two 32KB passes (rows 0-63 by waves 0,1; rows 64-127 by 2,3).
#pragma unroll
        for (int p = 0; p < 2; ++p) {
            __syncthreads();
            if ((w >> 1) == p) {
#pragma unroll
                for (int n = 0; n < 4; ++n) {
                    int c_blk = (w & 1) * 64 + n * 16 + cc;
                    float bv = bias[ctile * 128 + c_blk];
#pragma unroll
                    for (int m = 0; m < 4; ++m) {
#pragma unroll
                        for (int j = 0; j < 4; ++j) {
                            int rl = m * 16 + rb + j;           // 0..63
                            int byte = rl * 512 + ((((c_blk * 4) >> 4) ^ (rl & 7)) << 4) + ((c_blk * 4) & 15);
                            *reinterpret_cast<float*>(lc + byte) = acc[m][n][j] + bv;
                        }
                    }
                }
            }
            __syncthreads();
            int rl = tid >> 2;
            int gr = xtile * 128 + p * 64 + rl;
#pragma unroll
            for (int i = 0; i < 8; ++i) {
                int ch = (tid & 3) * 8 + i;
                uint4 v = *reinterpret_cast<uint4*>(lc + rl * 512 + ((ch ^ (rl & 7)) << 4));
                if (gr < M)
                    *reinterpret_cast<uint4*>((float*)Cout + (size_t)gr * ldc + ctile * 128 + ch * 4) = v;
            }
        }
    }
}

// ---------------------------------------------------------------------------
// Edge multisplit + CSR, all derived from per-block coarse histograms.
// ---------------------------------------------------------------------------
#define EPB 4096
#define NBMAX 128
#define FB 16            // fine col bands

__global__ __launch_bounds__(256) void hist_coarse(const int* __restrict__ row,
                                                   int* __restrict__ H, int E, int nblk, int NB) {
    __shared__ int h[NBMAX];
    int tid = threadIdx.x, blk = blockIdx.x;
    for (int b = tid; b < NB; b += 256) h[b] = 0;
    __syncthreads();
    int base = blk * EPB;
    int nloc = min(EPB, E - base);
    for (int k = tid; k < nloc; k += 256) atomicAdd(&h[row[base + k] >> 9], 1);
    __syncthreads();
    for (int b = tid; b < NB; b += 256) H[b * nblk + blk] = h[b];
}

__global__ __launch_bounds__(256) void bucket_totals(const int* __restrict__ H,
                                                     int* __restrict__ Tb, int nblk) {
    __shared__ int ws[4];
    int b = blockIdx.x, tid = threadIdx.x;
    int s = 0;
    for (int k = tid; k < nblk; k += 256) s += H[b * nblk + k];
#pragma unroll
    for (int off = 1; off < 64; off <<= 1) s += __shfl_xor(s, off, 64);
    if ((tid & 63) == 0) ws[tid >> 6] = s;
    __syncthreads();
    if (tid == 0) Tb[b] = ws[0] + ws[1] + ws[2] + ws[3];
}

__global__ void scan_buckets(const int* __restrict__ Tb, int* __restrict__ Cbase,
                             int NB, int* __restrict__ rowptr, int N) {
    int l = threadIdx.x;
    int carry = 0;
    for (int base = 0; base < NB; base += 64) {
        int idx = base + l;
        int v = (idx < NB) ? Tb[idx] : 0;
        int s = v;
#pragma unroll
        for (int off = 1; off < 64; off <<= 1) {
            int u = __shfl_up(s, off, 64);
            if (l >= off) s += u;
        }
        if (idx < NB) Cbase[idx] = s - v + carry;
        carry += __shfl(s, 63, 64);
    }
    if (l == 0) { Cbase[NB] = carry; rowptr[N] = carry; }
}

__global__ void scan_coarse(int* __restrict__ H, const int* __restrict__ Cbase, int nblk) {
    int b = blockIdx.x, l = threadIdx.x;
    int carry = Cbase[b];
    for (int s0 = 0; s0 < nblk; s0 += 64) {
        int idx = s0 + l;
        int v = (idx < nblk) ? H[b * nblk + idx] : 0;
        int s = v;
#pragma unroll
        for (int off = 1; off < 64; off <<= 1) {
            int u = __shfl_up(s, off, 64);
            if (l >= off) s += u;
        }
        if (idx < nblk) H[b * nblk + idx] = s - v + carry;
        carry += __shfl(s, 63, 64);
    }
}

__global__ __launch_bounds__(256) void scatter_coarse(const int* __restrict__ row,
                                                      const int* __restrict__ col,
                                                      const int* __restrict__ H,
                                                      unsigned* __restrict__ ebuf,
                                                      int E, int nblk, int NB) {
    __shared__ int h[NBMAX];
    __shared__ int lofs[NBMAX + 1];
    __shared__ int dstv[NBMAX];
    __shared__ unsigned rin[EPB];
    __shared__ unsigned rsort[EPB];
    int tid = threadIdx.x, blk = blockIdx.x;
    int base = blk * EPB;
    int nloc = min(EPB, E - base);

    for (int b = tid; b < NB; b += 256) h[b] = 0;
    __syncthreads();
    for (int k = tid; k < nloc; k += 256) {
        int r = row[base + k], c = col[base + k];
        rin[k] = ((unsigned)r << 16) | (unsigned)c;
        atomicAdd(&h[r >> 9], 1);
    }
    __syncthreads();
    if (tid == 0) {
        int run = 0;
        for (int b = 0; b < NB; ++b) { lofs[b] = run; run += h[b]; }
        lofs[NB] = run;
    }
    __syncthreads();
    for (int b = tid; b < NB; b += 256) { h[b] = lofs[b]; dstv[b] = H[b * nblk + blk]; }
    __syncthreads();
    for (int k = tid; k < nloc; k += 256) {
        unsigned rec = rin[k];
        int pos = atomicAdd(&h[rec >> 25], 1);
        rsort[pos] = rec;
    }
    __syncthreads();
    // parallel copy-out: thread k finds its bucket by binary search in lofs
    for (int k = tid; k < nloc; k += 256) {
        int lo = 0, hi = NB;
        while (hi - lo > 1) {
            int mid = (lo + hi) >> 1;
            if (lofs[mid] <= k) lo = mid; else hi = mid;
        }
        ebuf[dstv[lo] + (k - lofs[lo])] = rsort[k];
    }
}

// Fine pass per coarse bucket, keyed by (row, col-band): LDS segment
// histogram (512*FB) -> block exclusive scan -> rowptr -> banded scatter.
__global__ __launch_bounds__(256) void fine_fused(const unsigned* __restrict__ ebuf,
                                                  const int* __restrict__ Cbase,
                                                  int* __restrict__ rowptr,
                                                  int* __restrict__ ecol, int N) {
    __shared__ int lseg[512 * FB];                 // 32 KB: counts -> cursors
    __shared__ int ws[4];
    int b = blockIdx.x, tid = threadIdx.x, l = tid & 63, w = tid >> 6;
    int row0 = b << 9;
    int nr = min(512, N - row0);
    int base = Cbase[b], endp = Cbase[b + 1];

    for (int s = tid; s < 512 * FB; s += 256) lseg[s] = 0;
    __syncthreads();
    for (int k = base + tid; k < endp; k += 256) {
        unsigned rec = ebuf[k];
        int r = (rec >> 16) - row0;
        int band = ((rec & 0xFFFFu) * FB) >> 16;
        atomicAdd(&lseg[r * FB + band], 1);
    }
    __syncthreads();

    // block exclusive scan over 512*FB elements; thread owns contiguous chunk
    const int CH = 512 * FB / 256;                 // 32 per thread
    int base_t = tid * CH;
    int sum = 0;
#pragma unroll
    for (int u = 0; u < CH; ++u) sum += lseg[base_t + u];
    int s = sum;
#pragma unroll
    for (int off = 1; off < 64; off <<= 1) {
        int u = __shfl_up(s, off, 64);
        if (l >= off) s += u;
    }
    if (l == 63) ws[w] = s;
    __syncthreads();
    int woff = 0;
    for (int k = 0; k < w; ++k) woff += ws[k];
    int run = woff + s - sum;                      // exclusive prefix of chunk
#pragma unroll
    for (int u = 0; u < CH; ++u) {
        int c = lseg[base_t + u];
        lseg[base_t + u] = run;
        run += c;
    }
    __syncthreads();

    // rowptr: row r starts at its band-0 segment
    for (int r = tid; r < nr; r += 256) rowptr[row0 + r] = base + lseg[r * FB];
    __syncthreads();

    // banded scatter
    for (int k = base + tid; k < endp; k += 256) {
        unsigned rec = ebuf[k];
        int r = (rec >> 16) - row0;
        unsigned c = rec & 0xFFFFu;
        int band = (c * FB) >> 16;
        int rel = atomicAdd(&lseg[r * FB + band], 1);
        ecol[base + rel] = (int)c;
    }
}

// ---------------------------------------------------------------------------
// Fused sparse attention, one wave per node, depth-4 KV pipeline with a
// clamped column ring. Single launch.
// ---------------------------------------------------------------------------
__global__ __launch_bounds__(256) void attn_fused(
    const unsigned short* __restrict__ QKV,
    const int* __restrict__ rowptr, const int* __restrict__ ecol,
    unsigned short* __restrict__ attn_t, int N) {
    int i = blockIdx.x * 4 + (threadIdx.x >> 6);
    if (i >= N) return;
    int l = threadIdx.x & 63;

    ushort4 q4 = *reinterpret_cast<const ushort4*>(QKV + (size_t)i * 768 + l * 4);
    float q0 = bf2f(q4.x), q1 = bf2f(q4.y), q2 = bf2f(q4.z), q3 = bf2f(q4.w);

    int j = rowptr[i], end = rowptr[i + 1];
    float z = 0.f, a0 = 0.f, a1 = 0.f, a2 = 0.f, a3 = 0.f;

    if (j < end) {
        int last = end - 1;
#define CL(jj) ecol[(jj) < last ? (jj) : last]
#define KVL(c) (*reinterpret_cast<const u16x8*>(QKV + (size_t)(c) * 768 + 256 + l * 8))
        int cA = CL(j), cB = CL(j + 1), cC = CL(j + 2), cD = CL(j + 3);
        u16x8 kvA = KVL(cA), kvB = KVL(cB), kvC = KVL(cC), kvD = KVL(cD);
        int r0 = CL(j + 4), r1 = CL(j + 5), r2 = CL(j + 6), r3 = CL(j + 7);

#define STEP(KV) { \
        float s = q0 * bf2f(KV[0]) + q1 * bf2f(KV[1]) + q2 * bf2f(KV[2]) + q3 * bf2f(KV[3]); \
        s += __shfl_xor(s, 1, 64); \
        s += __shfl_xor(s, 2, 64); \
        s += __shfl_xor(s, 4, 64); \
        float wgt = __expf(s); \
        z += wgt; \
        a0 += wgt * bf2f(KV[4]); a1 += wgt * bf2f(KV[5]); \
        a2 += wgt * bf2f(KV[6]); a3 += wgt * bf2f(KV[7]); \
        KV = KVL(r0); r0 = r1; r1 = r2; r2 = r3; r3 = CL(j + 8); \
        ++j; }

        while (j < end) {
            STEP(kvA);
            if (j < end) STEP(kvB);
            if (j < end) STEP(kvC);
            if (j < end) STEP(kvD);
        }
#undef STEP
#undef KVL
#undef CL
    }

    float inv = (z > 0.f) ? 1.0f / z : 0.f;
    ushort4 o;
    o.x = f2bf(a0 * inv); o.y = f2bf(a1 * inv);
    o.z = f2bf(a2 * inv); o.w = f2bf(a3 * inv);
    int R = i >> 7, row = i & 127;
    int ks = l >> 4, kb = (l & 15) >> 1, j4 = (l & 1) * 4;
    *reinterpret_cast<ushort4*>(attn_t + (size_t)R * 32768 + ks * 8192 + kb * 1024 + row * 8 + j4) = o;
}

// ---------------------------------------------------------------------------
// Launch
// ---------------------------------------------------------------------------
extern "C" void kernel_launch(void* const* d_in, const int* in_sizes, int n_in,
                              void* d_out, int out_size, void* d_ws, size_t ws_size,
                              hipStream_t stream) {
    const float* x  = (const float*)d_in[0];
    const int*   row = (const int*)d_in[1];
    const int*   col = (const int*)d_in[2];
    const float* Wq = (const float*)d_in[3];
    const float* bq = (const float*)d_in[4];
    const float* Wk = (const float*)d_in[5];
    const float* bk = (const float*)d_in[6];
    const float* Wv = (const float*)d_in[7];
    const float* bv = (const float*)d_in[8];
    const float* Wo = (const float*)d_in[9];
    const float* bo = (const float*)d_in[10];
    int N = in_sizes[0] / DIM;
    int E = in_sizes[1];
    float* out = (float*)d_out;

    int Rtiles = (N + 127) / 128;
    int NB = (N + 511) >> 9;                       // coarse buckets (98)
    int nblk = (E + EPB - 1) / EPB;                // multisplit blocks (391)

    char* p = (char*)d_ws;
    auto alloc = [&](size_t bytes) {
        char* r = p;
        p += (bytes + 255) & ~(size_t)255;
        return r;
    };
    unsigned short* xt     = (unsigned short*)alloc((size_t)Rtiles * 32768 * 2);
    unsigned short* QKV    = (unsigned short*)alloc((size_t)N * 768 * 2);
    unsigned short* attn_t = (unsigned short*)alloc((size_t)Rtiles * 32768 * 2);
    unsigned short* WqkvT  = (unsigned short*)alloc((size_t)768 * DIM * 2);
    unsigned short* WoT    = (unsigned short*)alloc((size_t)DIM * DIM * 2);
    float* bqkv = (float*)alloc(768 * sizeof(float));
    int* rowptr = (int*)alloc((size_t)(N + 1) * sizeof(int));
    int* H      = (int*)alloc((size_t)NB * nblk * sizeof(int));
    int* Tb     = (int*)alloc((size_t)NB * sizeof(int));
    int* Cbase  = (int*)alloc((size_t)(NB + 1) * sizeof(int));
    unsigned* ebuf = (unsigned*)alloc((size_t)E * sizeof(unsigned));
    int* ecol   = (int*)alloc((size_t)E * sizeof(int));

    // fused prep: weights + biases + x conversion
    int prep_items = PREP_W0 + N * 32;
    prep_fused<<<(prep_items + 255) / 256, 256, 0, stream>>>(
        Wq, Wk, Wv, Wo, bq, bk, bv, x, WqkvT, WoT, bqkv, xt, N);

    // multisplit-derived CSR (col-banded fine order)
    hist_coarse<<<nblk, 256, 0, stream>>>(row, H, E, nblk, NB);
    bucket_totals<<<NB, 256, 0, stream>>>(H, Tb, nblk);
    scan_buckets<<<1, 64, 0, stream>>>(Tb, Cbase, NB, rowptr, N);
    scan_coarse<<<NB, 64, 0, stream>>>(H, Cbase, nblk);
    scatter_coarse<<<nblk, 256, 0, stream>>>(row, col, H, ebuf, E, nblk, NB);
    fine_fused<<<NB, 256, 0, stream>>>(ebuf, Cbase, rowptr, ecol, N);

    // fused QKV projection -> bf16 records [N][768]  (XCD-swizzled)
    gemm_tiled<1, 6><<<Rtiles * 6, 256, 0, stream>>>(xt, WqkvT, bqkv, QKV, N, 768);

    // fused sparse attention (single launch)
    attn_fused<<<(N + 3) / 4, 256, 0, stream>>>(QKV, rowptr, ecol, attn_t, N);

    // output projection -> f32 out  (XCD-swizzled)
    gemm_tiled<0, 2><<<Rtiles * 2, 256, 0, stream>>>(attn_t, WoT, bo, out, N, DIM);
}